// Round 6
// baseline (898.651 us; speedup 1.0000x reference)
//
#include <hip/hip_runtime.h>

// HGT encoder, MI355X — ROUND 6: all tensors FP32 (as the reference declares).
// Root cause of rounds 1-5: I misread fp32 buffers as bf16. NaN passthrough via
// fmaxf(NaN,0)=0 in the epilogue made 4 different pipelines produce bit-identical
// wrong output (absmax 9.9921875), and half-width u16 writes + an invisible
// mantissa-half sentinel completed the illusion. Multi-kernel launches are fine.
//
// Pipeline (per layer): q = X@Wq+bq; kv = X@Weff+beff (Ak/Av folded, exact);
// CSR-by-dst attention (one thread per (dst,head), no float atomics, fused
// softmax + exact GELU); out GEMM with fused sigmoid-skip + ReLU + residual,
// in-place on X (= d_out). Workspace ~168 MB fp32.

#define NTOT  80000
#define ETOT  600000
#define NSRC  120000

// ---------------- init ----------------

__global__ __launch_bounds__(256) void copy_init(
    const float* __restrict__ xg, const float* __restrict__ xd,
    const float* __restrict__ xr, float* __restrict__ X)
{
  int i = blockIdx.x * 256 + threadIdx.x;        // float4 units; 2,560,000 total
  if (i >= 2560000) return;
  const float* src; int off;
  if (i < 1600000)      { src = xg; off = i; }
  else if (i < 2240000) { src = xd; off = i - 1600000; }
  else                  { src = xr; off = i - 2240000; }
  ((float4*)X)[i] = ((const float4*)src)[off];
}

__global__ __launch_bounds__(256) void zero_cc(int* __restrict__ cnt, int* __restrict__ cur){
  int i = blockIdx.x * 256 + threadIdx.x;
  if (i < NTOT){ cnt[i] = 0; cur[i] = 0; }
}

// ---------------- CSR build ----------------

__global__ __launch_bounds__(256) void count_edges(const int* __restrict__ ei, int E, int offd,
                            int* __restrict__ cnt){
  int e = blockIdx.x * 256 + threadIdx.x;
  if (e < E) atomicAdd(&cnt[offd + ei[E + e]], 1);
}

__global__ __launch_bounds__(256) void scan_partial(const int* __restrict__ cnt,
                             int* __restrict__ rowp, int* __restrict__ bsum){
  __shared__ int s[256];
  int tid = threadIdx.x;
  int i = blockIdx.x * 256 + tid;
  int v = (i < NTOT) ? cnt[i] : 0;
  s[tid] = v; __syncthreads();
  for (int off = 1; off < 256; off <<= 1){
    int t = (tid >= off) ? s[tid - off] : 0;
    __syncthreads();
    s[tid] += t;
    __syncthreads();
  }
  if (i < NTOT) rowp[i] = s[tid] - v;            // exclusive within chunk
  if (tid == 255) bsum[blockIdx.x] = s[255];
}

// exclusive scan of up to 512 chunk totals with 256 threads (pair-scan)
__global__ __launch_bounds__(256) void scan_block(int* __restrict__ bsum, int nb){
  __shared__ int b[512];
  __shared__ int p[256];
  int tid = threadIdx.x;
  b[tid]       = (tid < nb)       ? bsum[tid]       : 0;
  b[tid + 256] = (tid + 256 < nb) ? bsum[tid + 256] : 0;
  __syncthreads();
  int pv = b[2*tid] + b[2*tid + 1];
  p[tid] = pv; __syncthreads();
  for (int off = 1; off < 256; off <<= 1){
    int t = (tid >= off) ? p[tid - off] : 0;
    __syncthreads();
    p[tid] += t;
    __syncthreads();
  }
  int excl = p[tid] - pv;
  int e0 = excl, e1 = excl + b[2*tid];
  __syncthreads();
  if (2*tid < nb)   bsum[2*tid]     = e0;
  if (2*tid+1 < nb) bsum[2*tid + 1] = e1;
}

__global__ __launch_bounds__(256) void scan_add(int* __restrict__ rowp, const int* __restrict__ bsum){
  int i = blockIdx.x * 256 + threadIdx.x;
  if (i < NTOT) rowp[i] += bsum[i >> 8];
}

__global__ __launch_bounds__(256) void scatter_edges(const int* __restrict__ ei, int E, int offd,
                              int rnoff, int rel,
                              const int* __restrict__ rowp, int* __restrict__ cur,
                              int* __restrict__ elist){
  int e = blockIdx.x * 256 + threadIdx.x;
  if (e >= E) return;
  int src = ei[e], dst = ei[E + e];
  int dstg = offd + dst;
  int pos = atomicAdd(&cur[dstg], 1);
  elist[rowp[dstg] + pos] = ((rnoff + src) << 2) | rel;
}

// ---------------- fold Ak/Av into K/V weights: Weff[lr] 128x256, beff[lr] 256 ----------------
// k_r = (X@Wk+bk)@Ak == X@(Wk.Ak) + bk.Ak  (exact fp32, per head D x D blocks)

__global__ __launch_bounds__(256) void build_weff(
    const float* __restrict__ Wkqv, const float* __restrict__ Ak,
    const float* __restrict__ Av, float* __restrict__ Weff)
{
  int lr = blockIdx.y;                  // l = lr>>2, r = lr&3
  int l = lr >> 2, r = lr & 3;
  int st = (r >= 2) ? 2 : 0;
  int elem = blockIdx.x * 256 + threadIdx.x;     // 0..32767: f*256 + j
  int f = elem >> 8, j = elem & 255;
  const float* W = Wkqv + (size_t)(l*3 + st) * 49152;
  float acc = 0.f;
  if (j < 128){
    int h = j >> 4, e = j & 15;
    const float* Am = Ak + (size_t)(l*4 + r) * 2048 + h*256;
#pragma unroll
    for (int d = 0; d < 16; d++) acc += W[f*384 + h*16 + d] * Am[d*16 + e];
  } else {
    int j2 = j - 128, h = j2 >> 4, e = j2 & 15;
    const float* Am = Av + (size_t)(l*4 + r) * 2048 + h*256;
#pragma unroll
    for (int d = 0; d < 16; d++) acc += W[f*384 + 256 + h*16 + d] * Am[d*16 + e];
  }
  Weff[(size_t)lr * 32768 + elem] = acc;
}

__global__ __launch_bounds__(256) void build_beff(
    const float* __restrict__ bkqv, const float* __restrict__ Ak,
    const float* __restrict__ Av, float* __restrict__ beff)
{
  int lr = blockIdx.x;
  int l = lr >> 2, r = lr & 3;
  int st = (r >= 2) ? 2 : 0;
  int j = threadIdx.x;                  // 0..255
  const float* b = bkqv + (size_t)(l*3 + st) * 384;
  float acc = 0.f;
  if (j < 128){
    int h = j >> 4, e = j & 15;
    const float* Am = Ak + (size_t)(l*4 + r) * 2048 + h*256;
#pragma unroll
    for (int d = 0; d < 16; d++) acc += b[h*16 + d] * Am[d*16 + e];
  } else {
    int j2 = j - 128, h = j2 >> 4, e = j2 & 15;
    const float* Am = Av + (size_t)(l*4 + r) * 2048 + h*256;
#pragma unroll
    for (int d = 0; d < 16; d++) acc += b[256 + h*16 + d] * Am[d*16 + e];
  }
  beff[lr * 256 + j] = acc;
}

// ---------------- GEMM: q = X @ Wkqv[:,128:256] + bkqv[128:256] ----------------

__global__ __launch_bounds__(256) void gemm_q(
    const float* __restrict__ A, const float* __restrict__ Wfull,
    const float* __restrict__ bias, float* __restrict__ C, int M)
{
  __shared__ float As[16][64];   // [k][m]
  __shared__ float Bs[16][64];   // [k][n]
  int tid = threadIdx.x;
  int bm = blockIdx.y * 64, bn = blockIdx.x * 64;   // grid.x = 2
  int tx = tid & 15, ty = tid >> 4;
  float acc[4][4] = {};
  int ar = tid >> 2, ac = (tid & 3) << 2;
  int br = tid >> 4, bc = (tid & 15) << 2;
  for (int k0 = 0; k0 < 128; k0 += 16){
    int arow = bm + ar;
    float4 av4 = make_float4(0.f,0.f,0.f,0.f);
    if (arow < M) av4 = *(const float4*)(A + (size_t)arow * 128 + k0 + ac);
    As[ac+0][ar]=av4.x; As[ac+1][ar]=av4.y; As[ac+2][ar]=av4.z; As[ac+3][ar]=av4.w;
    {
      float4 u = *(const float4*)(Wfull + (size_t)(k0 + br) * 384 + 128 + bn + bc);
      Bs[br][bc+0]=u.x; Bs[br][bc+1]=u.y; Bs[br][bc+2]=u.z; Bs[br][bc+3]=u.w;
    }
    __syncthreads();
#pragma unroll
    for (int kk = 0; kk < 16; kk++){
      float av[4], bv[4];
      *(float4*)av = *(const float4*)&As[kk][ty*4];
      *(float4*)bv = *(const float4*)&Bs[kk][tx*4];
#pragma unroll
      for (int i = 0; i < 4; i++)
#pragma unroll
        for (int j = 0; j < 4; j++) acc[i][j] += av[i] * bv[j];
    }
    __syncthreads();
  }
  int col = bn + tx*4;
  float b0=bias[128+col], b1=bias[128+col+1], b2=bias[128+col+2], b3=bias[128+col+3];
#pragma unroll
  for (int i = 0; i < 4; i++){
    int row = bm + ty*4 + i;
    if (row < M){
      float4 o = make_float4(acc[i][0]+b0, acc[i][1]+b1, acc[i][2]+b2, acc[i][3]+b3);
      *(float4*)(C + (size_t)row * 128 + col) = o;
    }
  }
}

// ---------------- GEMM: kv = X @ Weff + beff  (M x 256) ----------------

__global__ __launch_bounds__(256) void gemm_kv(
    const float* __restrict__ A, const float* __restrict__ B,
    const float* __restrict__ bias, float* __restrict__ C, int M)
{
  __shared__ float As[16][64];
  __shared__ float Bs[16][64];
  int tid = threadIdx.x;
  int bm = blockIdx.y * 64, bn = blockIdx.x * 64;   // grid.x = 4
  int tx = tid & 15, ty = tid >> 4;
  float acc[4][4] = {};
  int ar = tid >> 2, ac = (tid & 3) << 2;
  int br = tid >> 4, bc = (tid & 15) << 2;
  for (int k0 = 0; k0 < 128; k0 += 16){
    int arow = bm + ar;
    float4 av4 = make_float4(0.f,0.f,0.f,0.f);
    if (arow < M) av4 = *(const float4*)(A + (size_t)arow * 128 + k0 + ac);
    As[ac+0][ar]=av4.x; As[ac+1][ar]=av4.y; As[ac+2][ar]=av4.z; As[ac+3][ar]=av4.w;
    {
      float4 u = *(const float4*)(B + (size_t)(k0 + br) * 256 + bn + bc);
      Bs[br][bc+0]=u.x; Bs[br][bc+1]=u.y; Bs[br][bc+2]=u.z; Bs[br][bc+3]=u.w;
    }
    __syncthreads();
#pragma unroll
    for (int kk = 0; kk < 16; kk++){
      float av[4], bv[4];
      *(float4*)av = *(const float4*)&As[kk][ty*4];
      *(float4*)bv = *(const float4*)&Bs[kk][tx*4];
#pragma unroll
      for (int i = 0; i < 4; i++)
#pragma unroll
        for (int j = 0; j < 4; j++) acc[i][j] += av[i] * bv[j];
    }
    __syncthreads();
  }
  int col = bn + tx*4;
  float4 bb = *(const float4*)&bias[col];
#pragma unroll
  for (int i = 0; i < 4; i++){
    int row = bm + ty*4 + i;
    if (row < M){
      float4 o = make_float4(acc[i][0]+bb.x, acc[i][1]+bb.y, acc[i][2]+bb.z, acc[i][3]+bb.w);
      *(float4*)(C + (size_t)row * 256 + col) = o;
    }
  }
}

// ---------------- attention: one thread per (dst node, head); in-place q -> gelu(out) ----------------

__global__ __launch_bounds__(256) void attn_kernel(
    float* __restrict__ qg,                 // NTOT x 128: q in, gelu(out) out
    const float* __restrict__ kv,           // NSRC x 256: [k(128) | v(128)]
    const float* __restrict__ prel,         // + l*32
    const int* __restrict__ rowp, const int* __restrict__ cnt,
    const int* __restrict__ elist)
{
  int gid = blockIdx.x * 256 + threadIdx.x;
  int n = gid >> 3, h = gid & 7;
  if (n >= NTOT) return;
  float sc0 = prel[0*8+h]*0.25f, sc1 = prel[1*8+h]*0.25f,
        sc2 = prel[2*8+h]*0.25f, sc3 = prel[3*8+h]*0.25f;   // prel / sqrt(16)
  float q[16];
  const float* qp = qg + (size_t)n * 128 + h*16;
#pragma unroll
  for (int d = 0; d < 16; d += 4) *(float4*)&q[d] = *(const float4*)&qp[d];
  float acc[16] = {};
  float dsum = 0.f;
  int start = rowp[n], c = cnt[n];
  for (int ii = 0; ii < c; ii++){
    int v = elist[start + ii];
    int r = v & 3;
    const float* kp = kv + (size_t)(v >> 2) * 256 + h*16;
    float ke[16], ve[16];
#pragma unroll
    for (int d = 0; d < 16; d += 4){
      *(float4*)&ke[d] = *(const float4*)&kp[d];
      *(float4*)&ve[d] = *(const float4*)&kp[128 + d];
    }
    float a = 0.f;
#pragma unroll
    for (int d = 0; d < 16; d++) a += q[d] * ke[d];
    float s = (r == 0) ? sc0 : (r == 1) ? sc1 : (r == 2) ? sc2 : sc3;
    float ex = expf(a * s);     // softmax shift-invariant; |alpha| ~ O(1)
    dsum += ex;
#pragma unroll
    for (int d = 0; d < 16; d++) acc[d] += ex * ve[d];
  }
  float inv = (c > 0) ? 1.f / dsum : 0.f;
  float o[16];
#pragma unroll
  for (int d = 0; d < 16; d++){
    float x = acc[d] * inv;
    o[d] = 0.5f * x * (1.f + erff(x * 0.70710678118654752f));   // exact GELU
  }
  float* op = qg + (size_t)n * 128 + h*16;
#pragma unroll
  for (int d = 0; d < 16; d += 4) *(float4*)&op[d] = *(const float4*)&o[d];
}

// ---------------- out GEMM + sigmoid-skip + ReLU + residual (in-place on X) ----------------

__global__ __launch_bounds__(256) void gemm_out(
    const float* __restrict__ G, const float* __restrict__ W,
    const float* __restrict__ bias, const float* __restrict__ skip,
    float* __restrict__ X, int M)
{
  __shared__ float As[16][64];
  __shared__ float Bs[16][64];
  int tid = threadIdx.x;
  int bm = blockIdx.y * 64, bn = blockIdx.x * 64;   // grid.x = 2
  int tx = tid & 15, ty = tid >> 4;
  float acc[4][4] = {};
  int ar = tid >> 2, ac = (tid & 3) << 2;
  int br = tid >> 4, bc = (tid & 15) << 2;
  for (int k0 = 0; k0 < 128; k0 += 16){
    int arow = bm + ar;
    float4 av4 = make_float4(0.f,0.f,0.f,0.f);
    if (arow < M) av4 = *(const float4*)(G + (size_t)arow * 128 + k0 + ac);
    As[ac+0][ar]=av4.x; As[ac+1][ar]=av4.y; As[ac+2][ar]=av4.z; As[ac+3][ar]=av4.w;
    {
      float4 u = *(const float4*)(W + (size_t)(k0 + br) * 128 + bn + bc);
      Bs[br][bc+0]=u.x; Bs[br][bc+1]=u.y; Bs[br][bc+2]=u.z; Bs[br][bc+3]=u.w;
    }
    __syncthreads();
#pragma unroll
    for (int kk = 0; kk < 16; kk++){
      float av[4], bv[4];
      *(float4*)av = *(const float4*)&As[kk][ty*4];
      *(float4*)bv = *(const float4*)&Bs[kk][tx*4];
#pragma unroll
      for (int i = 0; i < 4; i++)
#pragma unroll
        for (int j = 0; j < 4; j++) acc[i][j] += av[i] * bv[j];
    }
    __syncthreads();
  }
  float a_s = 1.f / (1.f + expf(-skip[0]));
  float b_s = 1.f - a_s;
  int col = bn + tx*4;
  float bb0=bias[col], bb1=bias[col+1], bb2=bias[col+2], bb3=bias[col+3];
#pragma unroll
  for (int i = 0; i < 4; i++){
    int row = bm + ty*4 + i;
    if (row >= M) continue;
    float* xp = X + (size_t)row * 128 + col;
    float4 xo = *(const float4*)xp;
    float o0 = acc[i][0]+bb0, o1 = acc[i][1]+bb1, o2 = acc[i][2]+bb2, o3 = acc[i][3]+bb3;
    float4 res;
    res.x = fmaxf(a_s*o0 + b_s*xo.x, 0.f) + xo.x;
    res.y = fmaxf(a_s*o1 + b_s*xo.y, 0.f) + xo.y;
    res.z = fmaxf(a_s*o2 + b_s*xo.z, 0.f) + xo.z;
    res.w = fmaxf(a_s*o3 + b_s*xo.w, 0.f) + xo.w;
    *(float4*)xp = res;
  }
}

// ---------------- host ----------------

extern "C" void kernel_launch(void* const* d_in, const int* in_sizes, int n_in,
                              void* d_out, int out_size, void* d_ws, size_t ws_size,
                              hipStream_t stream)
{
  const float* xg   = (const float*)d_in[0];
  const float* xd   = (const float*)d_in[1];
  const float* xr_  = (const float*)d_in[2];
  const float* Wkqv = (const float*)d_in[3];
  const float* bkqv = (const float*)d_in[4];
  const float* Ak   = (const float*)d_in[5];
  const float* Av   = (const float*)d_in[6];
  const float* prel = (const float*)d_in[7];
  const float* Wout = (const float*)d_in[8];
  const float* bout = (const float*)d_in[9];
  const float* skip = (const float*)d_in[10];
  const int* ei[4] = {(const int*)d_in[11], (const int*)d_in[12],
                      (const int*)d_in[13], (const int*)d_in[14]};

  static const int NS_[3]  = {50000, 20000, 10000};
  static const int OFF_[4] = {0, 50000, 70000, 80000};
  static const int ES_[4]  = {300000, 150000, 100000, 50000};
  static const int ST_[4]  = {0, 0, 2, 2};
  static const int DT_[4]  = {0, 1, 0, 1};
  static const int RN_[4]  = {0, 50000, 100000, 110000};

  float* X = (float*)d_out;

  // workspace layout (~168 MB), ints first
  char* p = (char*)d_ws;
  auto alloc = [&](size_t b)->void*{ void* r = (void*)p; p += (b + 255) & ~(size_t)255; return r; };
  int*   cnt  = (int*)  alloc((size_t)NTOT * 4);
  int*   rowp = (int*)  alloc((size_t)NTOT * 4);
  int*   cur  = (int*)  alloc((size_t)NTOT * 4);
  int*   bsum = (int*)  alloc(512 * 4);
  int*   elist= (int*)  alloc((size_t)ETOT * 4);
  float* Weff = (float*)alloc((size_t)8 * 32768 * 4);
  float* beff = (float*)alloc((size_t)8 * 256 * 4);
  float* qg   = (float*)alloc((size_t)NTOT * 128 * 4);    //  41 MB
  float* kv   = (float*)alloc((size_t)NSRC * 256 * 4);    // 123 MB
  (void)ws_size; (void)in_sizes; (void)n_in; (void)out_size;

  // X <- concat(x_gene, x_disease, x_drug); zero cnt/cur
  copy_init<<<10000, 256, 0, stream>>>(xg, xd, xr_, X);
  zero_cc<<<313, 256, 0, stream>>>(cnt, cur);

  // CSR by destination (edges fixed -> build once per call)
  for (int r = 0; r < 4; r++)
    count_edges<<<(ES_[r]+255)/256, 256, 0, stream>>>(ei[r], ES_[r], OFF_[DT_[r]], cnt);
  scan_partial<<<313, 256, 0, stream>>>(cnt, rowp, bsum);
  scan_block<<<1, 256, 0, stream>>>(bsum, 313);
  scan_add<<<313, 256, 0, stream>>>(rowp, bsum);
  for (int r = 0; r < 4; r++)
    scatter_edges<<<(ES_[r]+255)/256, 256, 0, stream>>>(ei[r], ES_[r], OFF_[DT_[r]],
                                                        RN_[r], r, rowp, cur, elist);

  // effective K/V weights for all (l, r)
  build_weff<<<dim3(128, 8), 256, 0, stream>>>(Wkqv, Ak, Av, Weff);
  build_beff<<<8, 256, 0, stream>>>(bkqv, Ak, Av, beff);

  for (int l = 0; l < 2; l++){
    for (int t = 0; t < 3; t++)
      gemm_q<<<dim3(2, (NS_[t]+63)/64), 256, 0, stream>>>(
          X + (size_t)OFF_[t]*128,
          Wkqv + (size_t)(l*3 + t)*49152,
          bkqv + (size_t)(l*3 + t)*384,
          qg + (size_t)OFF_[t]*128,
          NS_[t]);
    for (int r = 0; r < 4; r++){
      int lr = l*4 + r, st = ST_[r];
      gemm_kv<<<dim3(4, (NS_[st]+63)/64), 256, 0, stream>>>(
          X + (size_t)OFF_[st]*128,
          Weff + (size_t)lr * 32768,
          beff + (size_t)lr * 256,
          kv + (size_t)RN_[r]*256,
          NS_[st]);
    }
    attn_kernel<<<(NTOT*8)/256, 256, 0, stream>>>(qg, kv, prel + l*32, rowp, cnt, elist);
    for (int t = 0; t < 3; t++)
      gemm_out<<<dim3(2, (NS_[t]+63)/64), 256, 0, stream>>>(
          qg + (size_t)OFF_[t]*128,
          Wout + (size_t)(l*3 + t)*16384,
          bout + (size_t)(l*3 + t)*128,
          skip + (l*3 + t),
          X + (size_t)OFF_[t]*128,
          NS_[t]);
  }
}

// Round 8
// 604.549 us; speedup vs baseline: 1.4865x; 1.4865x over previous
//
#include <hip/hip_runtime.h>

// HGT encoder, MI355X — ROUND 8: fix MFMA tile coverage.
// R7 bug: 64-wide tiles but NT=2 fragment loops computed only cols 0..31 of
// each tile in the q- and out-GEMMs (half of q = poison, half of X missed its
// update) -> absmax 3.06. Fix: 4 n-fragments per 64-wide tile in ALL GEMMs.
// Layouts (guide-verified): A[m=lane&15][k=quad*8+j], B[k=quad*8+j][n=lane&15],
// D[row=quad*4+reg][col=lane&15].

#define NTOT  80000
#define ETOT  600000
#define NSRC  120000

typedef unsigned short u16;
typedef unsigned int   u32;
typedef __attribute__((ext_vector_type(8))) short short8;
typedef __attribute__((ext_vector_type(4))) float f32x4;

__device__ __forceinline__ float bf2f(u16 u){
  union { u32 i; float f; } v; v.i = ((u32)u) << 16; return v.f;
}
__device__ __forceinline__ u16 f2bf(float f){
  union { float f; u32 i; } v; v.f = f;
  u32 x = v.i;
  return (u16)((x + 0x7fffu + ((x >> 16) & 1u)) >> 16);   // RNE
}
__device__ __forceinline__ void unpack8(const u16* p, float* o){
  uint4 a = *(const uint4*)p;
  union { u32 i; float f; } t;
  t.i = a.x << 16;        o[0]=t.f;  t.i = a.x & 0xffff0000u; o[1]=t.f;
  t.i = a.y << 16;        o[2]=t.f;  t.i = a.y & 0xffff0000u; o[3]=t.f;
  t.i = a.z << 16;        o[4]=t.f;  t.i = a.z & 0xffff0000u; o[5]=t.f;
  t.i = a.w << 16;        o[6]=t.f;  t.i = a.w & 0xffff0000u; o[7]=t.f;
}
__device__ __forceinline__ void load16bf(const u16* p, float* o){
  unpack8(p, o); unpack8(p + 8, o + 8);
}

// ---------------- init ----------------

__global__ __launch_bounds__(256) void copy_init(
    const float* __restrict__ xg, const float* __restrict__ xd,
    const float* __restrict__ xr, float* __restrict__ X)
{
  int i = blockIdx.x * 256 + threadIdx.x;        // float4 units; 2,560,000 total
  if (i >= 2560000) return;
  const float* src; int off;
  if (i < 1600000)      { src = xg; off = i; }
  else if (i < 2240000) { src = xd; off = i - 1600000; }
  else                  { src = xr; off = i - 2240000; }
  ((float4*)X)[i] = ((const float4*)src)[off];
}

__global__ __launch_bounds__(256) void zero_cc(int* __restrict__ cnt, int* __restrict__ cur){
  int i = blockIdx.x * 256 + threadIdx.x;
  if (i < NTOT){ cnt[i] = 0; cur[i] = 0; }
}

// ---------------- CSR build ----------------

__global__ __launch_bounds__(256) void count_edges(const int* __restrict__ ei, int E, int offd,
                            int* __restrict__ cnt){
  int e = blockIdx.x * 256 + threadIdx.x;
  if (e < E) atomicAdd(&cnt[offd + ei[E + e]], 1);
}

__global__ __launch_bounds__(256) void scan_partial(const int* __restrict__ cnt,
                             int* __restrict__ rowp, int* __restrict__ bsum){
  __shared__ int s[256];
  int tid = threadIdx.x;
  int i = blockIdx.x * 256 + tid;
  int v = (i < NTOT) ? cnt[i] : 0;
  s[tid] = v; __syncthreads();
  for (int off = 1; off < 256; off <<= 1){
    int t = (tid >= off) ? s[tid - off] : 0;
    __syncthreads();
    s[tid] += t;
    __syncthreads();
  }
  if (i < NTOT) rowp[i] = s[tid] - v;
  if (tid == 255) bsum[blockIdx.x] = s[255];
}

__global__ __launch_bounds__(256) void scan_block(int* __restrict__ bsum, int nb){
  __shared__ int b[512];
  __shared__ int p[256];
  int tid = threadIdx.x;
  b[tid]       = (tid < nb)       ? bsum[tid]       : 0;
  b[tid + 256] = (tid + 256 < nb) ? bsum[tid + 256] : 0;
  __syncthreads();
  int pv = b[2*tid] + b[2*tid + 1];
  p[tid] = pv; __syncthreads();
  for (int off = 1; off < 256; off <<= 1){
    int t = (tid >= off) ? p[tid - off] : 0;
    __syncthreads();
    p[tid] += t;
    __syncthreads();
  }
  int excl = p[tid] - pv;
  int e0 = excl, e1 = excl + b[2*tid];
  __syncthreads();
  if (2*tid < nb)   bsum[2*tid]     = e0;
  if (2*tid+1 < nb) bsum[2*tid + 1] = e1;
}

__global__ __launch_bounds__(256) void scan_add(int* __restrict__ rowp, const int* __restrict__ bsum){
  int i = blockIdx.x * 256 + threadIdx.x;
  if (i < NTOT) rowp[i] += bsum[i >> 8];
}

__global__ __launch_bounds__(256) void scatter_edges(const int* __restrict__ ei, int E, int offd,
                              int rnoff, int rel,
                              const int* __restrict__ rowp, int* __restrict__ cur,
                              int* __restrict__ elist){
  int e = blockIdx.x * 256 + threadIdx.x;
  if (e >= E) return;
  int src = ei[e], dst = ei[E + e];
  int dstg = offd + dst;
  int pos = atomicAdd(&cur[dstg], 1);
  elist[rowp[dstg] + pos] = ((rnoff + src) << 2) | rel;
}

// ---------------- fold Ak/Av into K/V weights (fp32, exact) ----------------

__global__ __launch_bounds__(256) void build_weff(
    const float* __restrict__ Wkqv, const float* __restrict__ Ak,
    const float* __restrict__ Av, float* __restrict__ Weff)
{
  int lr = blockIdx.y;
  int l = lr >> 2, r = lr & 3;
  int st = (r >= 2) ? 2 : 0;
  int elem = blockIdx.x * 256 + threadIdx.x;     // f*256 + j
  int f = elem >> 8, j = elem & 255;
  const float* W = Wkqv + (size_t)(l*3 + st) * 49152;
  float acc = 0.f;
  if (j < 128){
    int h = j >> 4, e = j & 15;
    const float* Am = Ak + (size_t)(l*4 + r) * 2048 + h*256;
#pragma unroll
    for (int d = 0; d < 16; d++) acc += W[f*384 + h*16 + d] * Am[d*16 + e];
  } else {
    int j2 = j - 128, h = j2 >> 4, e = j2 & 15;
    const float* Am = Av + (size_t)(l*4 + r) * 2048 + h*256;
#pragma unroll
    for (int d = 0; d < 16; d++) acc += W[f*384 + 256 + h*16 + d] * Am[d*16 + e];
  }
  Weff[(size_t)lr * 32768 + elem] = acc;
}

__global__ __launch_bounds__(256) void build_beff(
    const float* __restrict__ bkqv, const float* __restrict__ Ak,
    const float* __restrict__ Av, float* __restrict__ beff)
{
  int lr = blockIdx.x;
  int l = lr >> 2, r = lr & 3;
  int st = (r >= 2) ? 2 : 0;
  int j = threadIdx.x;
  const float* b = bkqv + (size_t)(l*3 + st) * 384;
  float acc = 0.f;
  if (j < 128){
    int h = j >> 4, e = j & 15;
    const float* Am = Ak + (size_t)(l*4 + r) * 2048 + h*256;
#pragma unroll
    for (int d = 0; d < 16; d++) acc += b[h*16 + d] * Am[d*16 + e];
  } else {
    int j2 = j - 128, h = j2 >> 4, e = j2 & 15;
    const float* Am = Av + (size_t)(l*4 + r) * 2048 + h*256;
#pragma unroll
    for (int d = 0; d < 16; d++) acc += b[256 + h*16 + d] * Am[d*16 + e];
  }
  beff[lr * 256 + j] = acc;
}

// ---------------- MFMA GEMM: C(bf16) = A(fp32 Mx128) @ B(fp32 128xN) + bias ----------------
// 64x64 tile / block, 4 waves x 16 rows; 4 n-frags x 16 cols = full 64-wide tile.

#define BTSTR 136   // u16 stride of LDS B^T rows (272 B: 16B-aligned)

__global__ __launch_bounds__(256) void mfma_gemm(
    const float* __restrict__ A, const float* __restrict__ B, int ldb,
    const float* __restrict__ bias, u16* __restrict__ C, int ldc, int M)
{
  __shared__ u16 BT[64 * BTSTR];
  int tid = threadIdx.x;
  int bn = blockIdx.x * 64, bm = blockIdx.y * 64;
  { // stage B^T (bf16): coalesced global reads, transpose into LDS
    int n = tid & 63, k0 = tid >> 6;
#pragma unroll
    for (int i = 0; i < 32; i++){
      int k = k0 + i*4;
      BT[n*BTSTR + k] = f2bf(B[(size_t)k*ldb + bn + n]);
    }
  }
  __syncthreads();
  int lane = tid & 63, wave = tid >> 6;
  int quad = lane >> 4, lm = lane & 15;
  int row = bm + wave*16 + lm;
  short8 af[4];
  if (row < M){
    const float* ap = A + (size_t)row*128 + quad*8;
#pragma unroll
    for (int c = 0; c < 4; c++){
      f32x4 lo = *(const f32x4*)(ap + c*32);
      f32x4 hi = *(const f32x4*)(ap + c*32 + 4);
      short8 t;
      t[0]=(short)f2bf(lo[0]); t[1]=(short)f2bf(lo[1]);
      t[2]=(short)f2bf(lo[2]); t[3]=(short)f2bf(lo[3]);
      t[4]=(short)f2bf(hi[0]); t[5]=(short)f2bf(hi[1]);
      t[6]=(short)f2bf(hi[2]); t[7]=(short)f2bf(hi[3]);
      af[c] = t;
    }
  } else {
    short8 z = {0,0,0,0,0,0,0,0};
#pragma unroll
    for (int c = 0; c < 4; c++) af[c] = z;
  }
  f32x4 acc[4];
#pragma unroll
  for (int nt = 0; nt < 4; nt++) acc[nt] = (f32x4){0.f,0.f,0.f,0.f};
#pragma unroll
  for (int nt = 0; nt < 4; nt++){
    const u16* bp = &BT[(nt*16 + lm) * BTSTR + quad*8];
#pragma unroll
    for (int c = 0; c < 4; c++){
      short8 bf = *(const short8*)(bp + c*32);
      acc[nt] = __builtin_amdgcn_mfma_f32_16x16x32_bf16(af[c], bf, acc[nt], 0, 0, 0);
    }
  }
#pragma unroll
  for (int nt = 0; nt < 4; nt++){
    int col = bn + nt*16 + lm;
    float bb = bias[col];
#pragma unroll
    for (int i = 0; i < 4; i++){
      int r = bm + wave*16 + quad*4 + i;
      if (r < M) C[(size_t)r*ldc + col] = f2bf(acc[nt][i] + bb);
    }
  }
}

// ---------------- MFMA out GEMM: A = G(bf16), epilogue skip+relu+residual on X(fp32) ----------------

__global__ __launch_bounds__(256) void mfma_gemm_out(
    const u16* __restrict__ G, const float* __restrict__ B,
    const float* __restrict__ bias, const float* __restrict__ skip,
    float* __restrict__ X, int M)
{
  __shared__ u16 BT[64 * BTSTR];
  int tid = threadIdx.x;
  int bn = blockIdx.x * 64, bm = blockIdx.y * 64;
  {
    int n = tid & 63, k0 = tid >> 6;
#pragma unroll
    for (int i = 0; i < 32; i++){
      int k = k0 + i*4;
      BT[n*BTSTR + k] = f2bf(B[(size_t)k*128 + bn + n]);
    }
  }
  __syncthreads();
  int lane = tid & 63, wave = tid >> 6;
  int quad = lane >> 4, lm = lane & 15;
  int row = bm + wave*16 + lm;
  short8 af[4];
  if (row < M){
    const u16* gp = G + (size_t)row*128 + quad*8;
#pragma unroll
    for (int c = 0; c < 4; c++) af[c] = *(const short8*)(gp + c*32);  // native bf16
  } else {
    short8 z = {0,0,0,0,0,0,0,0};
#pragma unroll
    for (int c = 0; c < 4; c++) af[c] = z;
  }
  f32x4 acc[4];
#pragma unroll
  for (int nt = 0; nt < 4; nt++) acc[nt] = (f32x4){0.f,0.f,0.f,0.f};
#pragma unroll
  for (int nt = 0; nt < 4; nt++){
    const u16* bp = &BT[(nt*16 + lm) * BTSTR + quad*8];
#pragma unroll
    for (int c = 0; c < 4; c++){
      short8 bf = *(const short8*)(bp + c*32);
      acc[nt] = __builtin_amdgcn_mfma_f32_16x16x32_bf16(af[c], bf, acc[nt], 0, 0, 0);
    }
  }
  float a_s = 1.f / (1.f + expf(-skip[0]));
  float b_s = 1.f - a_s;
#pragma unroll
  for (int nt = 0; nt < 4; nt++){
    int col = bn + nt*16 + lm;
    float bb = bias[col];
#pragma unroll
    for (int i = 0; i < 4; i++){
      int r = bm + wave*16 + quad*4 + i;
      if (r < M){
        float* xp = X + (size_t)r*128 + col;
        float x = *xp;
        float o = acc[nt][i] + bb;
        *xp = fmaxf(a_s*o + b_s*x, 0.f) + x;
      }
    }
  }
}

// ---------------- attention: one thread per (dst,head); qg/kv bf16 ----------------

__global__ __launch_bounds__(256) void attn_kernel(
    u16* __restrict__ qg,                   // NTOT x 128 bf16: q in, gelu(out) out
    const u16* __restrict__ kv,             // NSRC x 256 bf16: [k | v]
    const float* __restrict__ prel,         // + l*32
    const int* __restrict__ rowp, const int* __restrict__ cnt,
    const int* __restrict__ elist)
{
  int gid = blockIdx.x * 256 + threadIdx.x;
  int n = gid >> 3, h = gid & 7;
  if (n >= NTOT) return;
  float sc0 = prel[0*8+h]*0.25f, sc1 = prel[1*8+h]*0.25f,
        sc2 = prel[2*8+h]*0.25f, sc3 = prel[3*8+h]*0.25f;
  float q[16];
  load16bf(qg + (size_t)n * 128 + h*16, q);
  float acc[16] = {};
  float dsum = 0.f;
  int start = rowp[n], c = cnt[n];
  for (int ii = 0; ii < c; ii++){
    int v = elist[start + ii];
    int r = v & 3;
    const u16* kp = kv + (size_t)(v >> 2) * 256 + h*16;
    float ke[16], ve[16];
    load16bf(kp, ke);
    load16bf(kp + 128, ve);
    float a = 0.f;
#pragma unroll
    for (int d = 0; d < 16; d++) a += q[d] * ke[d];
    float s = (r == 0) ? sc0 : (r == 1) ? sc1 : (r == 2) ? sc2 : sc3;
    float ex = expf(a * s);
    dsum += ex;
#pragma unroll
    for (int d = 0; d < 16; d++) acc[d] += ex * ve[d];
  }
  float inv = (c > 0) ? 1.f / dsum : 0.f;
  u16 o[16];
#pragma unroll
  for (int d = 0; d < 16; d++){
    float x = acc[d] * inv;
    o[d] = f2bf(0.5f * x * (1.f + erff(x * 0.70710678118654752f)));
  }
  uint4 p0, p1;
  p0.x = o[0]|(o[1]<<16);   p0.y = o[2]|(o[3]<<16);
  p0.z = o[4]|(o[5]<<16);   p0.w = o[6]|(o[7]<<16);
  p1.x = o[8]|(o[9]<<16);   p1.y = o[10]|(o[11]<<16);
  p1.z = o[12]|(o[13]<<16); p1.w = o[14]|(o[15]<<16);
  u16* op = qg + (size_t)n * 128 + h*16;
  *(uint4*)op = p0; *(uint4*)(op + 8) = p1;
}

// ---------------- host ----------------

extern "C" void kernel_launch(void* const* d_in, const int* in_sizes, int n_in,
                              void* d_out, int out_size, void* d_ws, size_t ws_size,
                              hipStream_t stream)
{
  const float* xg   = (const float*)d_in[0];
  const float* xd   = (const float*)d_in[1];
  const float* xr_  = (const float*)d_in[2];
  const float* Wkqv = (const float*)d_in[3];
  const float* bkqv = (const float*)d_in[4];
  const float* Ak   = (const float*)d_in[5];
  const float* Av   = (const float*)d_in[6];
  const float* prel = (const float*)d_in[7];
  const float* Wout = (const float*)d_in[8];
  const float* bout = (const float*)d_in[9];
  const float* skip = (const float*)d_in[10];
  const int* ei[4] = {(const int*)d_in[11], (const int*)d_in[12],
                      (const int*)d_in[13], (const int*)d_in[14]};

  static const int NS_[3]  = {50000, 20000, 10000};
  static const int OFF_[4] = {0, 50000, 70000, 80000};
  static const int ES_[4]  = {300000, 150000, 100000, 50000};
  static const int ST_[4]  = {0, 0, 2, 2};
  static const int DT_[4]  = {0, 1, 0, 1};
  static const int RN_[4]  = {0, 50000, 100000, 110000};

  float* X = (float*)d_out;

  char* p = (char*)d_ws;
  auto alloc = [&](size_t b)->void*{ void* r = (void*)p; p += (b + 255) & ~(size_t)255; return r; };
  int*   cnt  = (int*)  alloc((size_t)NTOT * 4);
  int*   rowp = (int*)  alloc((size_t)NTOT * 4);
  int*   cur  = (int*)  alloc((size_t)NTOT * 4);
  int*   bsum = (int*)  alloc(512 * 4);
  int*   elist= (int*)  alloc((size_t)ETOT * 4);
  float* Weff = (float*)alloc((size_t)8 * 32768 * 4);
  float* beff = (float*)alloc((size_t)8 * 256 * 4);
  u16*   qg   = (u16*)  alloc((size_t)NTOT * 128 * 2);    // 20.5 MB bf16
  u16*   kv   = (u16*)  alloc((size_t)NSRC * 256 * 2);    // 61.4 MB bf16
  (void)ws_size; (void)in_sizes; (void)n_in; (void)out_size;

  copy_init<<<10000, 256, 0, stream>>>(xg, xd, xr_, X);
  zero_cc<<<313, 256, 0, stream>>>(cnt, cur);

  for (int r = 0; r < 4; r++)
    count_edges<<<(ES_[r]+255)/256, 256, 0, stream>>>(ei[r], ES_[r], OFF_[DT_[r]], cnt);
  scan_partial<<<313, 256, 0, stream>>>(cnt, rowp, bsum);
  scan_block<<<1, 256, 0, stream>>>(bsum, 313);
  scan_add<<<313, 256, 0, stream>>>(rowp, bsum);
  for (int r = 0; r < 4; r++)
    scatter_edges<<<(ES_[r]+255)/256, 256, 0, stream>>>(ei[r], ES_[r], OFF_[DT_[r]],
                                                        RN_[r], r, rowp, cur, elist);

  build_weff<<<dim3(128, 8), 256, 0, stream>>>(Wkqv, Ak, Av, Weff);
  build_beff<<<8, 256, 0, stream>>>(bkqv, Ak, Av, beff);

  for (int l = 0; l < 2; l++){
    for (int t = 0; t < 3; t++)
      mfma_gemm<<<dim3(2, (NS_[t]+63)/64), 256, 0, stream>>>(
          X + (size_t)OFF_[t]*128,
          Wkqv + (size_t)(l*3 + t)*49152 + 128, 384,     // q columns
          bkqv + (size_t)(l*3 + t)*384 + 128,
          qg + (size_t)OFF_[t]*128, 128,
          NS_[t]);
    for (int r = 0; r < 4; r++){
      int lr = l*4 + r, st = ST_[r];
      mfma_gemm<<<dim3(4, (NS_[st]+63)/64), 256, 0, stream>>>(
          X + (size_t)OFF_[st]*128,
          Weff + (size_t)lr * 32768, 256,
          beff + (size_t)lr * 256,
          kv + (size_t)RN_[r]*256, 256,
          NS_[st]);
    }
    attn_kernel<<<(NTOT*8)/256, 256, 0, stream>>>(qg, kv, prel + l*32, rowp, cnt, elist);
    for (int t = 0; t < 3; t++)
      mfma_gemm_out<<<dim3(2, (NS_[t]+63)/64), 256, 0, stream>>>(
          qg + (size_t)OFF_[t]*128,
          Wout + (size_t)(l*3 + t)*16384,
          bout + (size_t)(l*3 + t)*128,
          skip + (l*3 + t),
          X + (size_t)OFF_[t]*128,
          NS_[t]);
  }
}